// Round 1
// baseline (133.171 us; speedup 1.0000x reference)
//
#include <hip/hip_runtime.h>

#define N_FEAT 2048
#define ORDER 8
#define BATCH 8192
#define BLOCK 256
#define RPW 2            // rows per wave
#define CHUNKS 8         // 8 v4f chunks/lane/row: 64 lanes * 4 * 8 = 2048 cols

typedef float v4f __attribute__((ext_vector_type(4)));

__device__ __forceinline__ float dot4(v4f a, v4f b) {
    return a.x * b.x + a.y * b.y + a.z * b.z + a.w * b.w;
}

// Prep kernel (1 block): normalize the 8 reflection vectors into ws.
__global__ __launch_bounds__(BLOCK) void prep_kernel(
    const float* __restrict__ v, float* __restrict__ vn) {
    const int tid = threadIdx.x;
    const int lane = tid & 63, wid = tid >> 6;

    v4f a0[ORDER], a1[ORDER];
    #pragma unroll
    for (int i = 0; i < ORDER; ++i) {
        a0[i] = *(const v4f*)(v + (size_t)i * N_FEAT + tid * 4);
        a1[i] = *(const v4f*)(v + (size_t)i * N_FEAT + 1024 + tid * 4);
    }
    float ss[ORDER];
    #pragma unroll
    for (int i = 0; i < ORDER; ++i)
        ss[i] = dot4(a0[i], a0[i]) + dot4(a1[i], a1[i]);
    #pragma unroll
    for (int o = 32; o > 0; o >>= 1)
        #pragma unroll
        for (int i = 0; i < ORDER; ++i) ss[i] += __shfl_down(ss[i], o, 64);

    __shared__ float red[4][ORDER];
    if (lane == 0) {
        #pragma unroll
        for (int i = 0; i < ORDER; ++i) red[wid][i] = ss[i];
    }
    __syncthreads();
    #pragma unroll
    for (int i = 0; i < ORDER; ++i) {
        const float inv = 1.0f / sqrtf(red[0][i] + red[1][i] + red[2][i] + red[3][i]);
        *(v4f*)(vn + (size_t)i * N_FEAT + tid * 4) = a0[i] * inv;
        *(v4f*)(vn + (size_t)i * N_FEAT + 1024 + tid * 4) = a1[i] * inv;
    }
}

// Apply kernel — wave-autonomous: each wave owns RPW full rows (lane l holds
// 8 strided v4f chunks per row, col = k*256 + l*4, coalesced 1 KiB/chunk).
// Dot product = in-wave __shfl_xor butterfly (sum lands in ALL lanes), so
// there is NO LDS, NO __syncthreads, NO lane-0 broadcast — the 8 serialized
// reflections no longer drain the memory pipeline at block barriers, and the
// compiler can hoist iteration i+1's vn loads over iteration i's shuffles.
__global__ __launch_bounds__(BLOCK) void orth_apply_kernel(
    const float* __restrict__ x, const float* __restrict__ vn,
    const float* __restrict__ d, const float* __restrict__ bias,
    float* __restrict__ y) {
    const int lane = threadIdx.x & 63;
    const int wid  = threadIdx.x >> 6;
    const int wg   = blockIdx.x * (BLOCK / 64) + wid;   // global wave id
    const size_t row0 = (size_t)wg * RPW;
    const int coff = lane * 4;

    // Load RPW rows of x: 16 independent nontemporal 16B loads in flight
    // (x is read-once; nt keeps the 64 KB vn hot in L1/L2).
    v4f z[RPW][CHUNKS];
    #pragma unroll
    for (int r = 0; r < RPW; ++r)
        #pragma unroll
        for (int k = 0; k < CHUNKS; ++k)
            z[r][k] = __builtin_nontemporal_load(
                (const v4f*)(x + (row0 + r) * N_FEAT + k * 256 + coff));

    #pragma unroll
    for (int i = 0; i < ORDER; ++i) {
        const float* vr = vn + (size_t)i * N_FEAT;
        v4f a[CHUNKS];
        #pragma unroll
        for (int k = 0; k < CHUNKS; ++k)
            a[k] = *(const v4f*)(vr + k * 256 + coff);

        float p[RPW];
        #pragma unroll
        for (int r = 0; r < RPW; ++r) {
            // balanced tree over the 8 chunk dots (keeps fp32 error ~ current)
            const float t0 = dot4(z[r][0], a[0]) + dot4(z[r][1], a[1]);
            const float t1 = dot4(z[r][2], a[2]) + dot4(z[r][3], a[3]);
            const float t2 = dot4(z[r][4], a[4]) + dot4(z[r][5], a[5]);
            const float t3 = dot4(z[r][6], a[6]) + dot4(z[r][7], a[7]);
            p[r] = (t0 + t1) + (t2 + t3);
        }

        // In-wave butterfly: all 64 lanes end with the full row sum.
        #pragma unroll
        for (int o = 32; o > 0; o >>= 1)
            #pragma unroll
            for (int r = 0; r < RPW; ++r)
                p[r] += __shfl_xor(p[r], o, 64);

        #pragma unroll
        for (int r = 0; r < RPW; ++r) {
            const float s = -2.0f * p[r];
            #pragma unroll
            for (int k = 0; k < CHUNKS; ++k)
                z[r][k] += s * a[k];
        }
    }

    // Epilogue: y = z * d + bias, nontemporal (write-once, no re-read).
    #pragma unroll
    for (int k = 0; k < CHUNKS; ++k) {
        const v4f dk = *(const v4f*)(d + k * 256 + coff);
        const v4f bk = *(const v4f*)(bias + k * 256 + coff);
        #pragma unroll
        for (int r = 0; r < RPW; ++r) {
            v4f o = z[r][k] * dk + bk;
            __builtin_nontemporal_store(
                o, (v4f*)(y + (row0 + r) * N_FEAT + k * 256 + coff));
        }
    }
}

extern "C" void kernel_launch(void* const* d_in, const int* in_sizes, int n_in,
                              void* d_out, int out_size, void* d_ws, size_t ws_size,
                              hipStream_t stream) {
    const float* x    = (const float*)d_in[0];  // [8192, 2048]
    const float* v    = (const float*)d_in[1];  // [8, 2048]
    const float* d    = (const float*)d_in[2];  // [2048]
    const float* bias = (const float*)d_in[3];  // [2048]
    float* y  = (float*)d_out;                  // [8192, 2048]
    float* vn = (float*)d_ws;                   // [8, 2048]

    prep_kernel<<<1, BLOCK, 0, stream>>>(v, vn);
    // 8 rows/block (4 waves * RPW) -> 1024 blocks; ~115 VGPR -> 4 waves/SIMD,
    // all 8192 rows resident in one round, zero barriers in the hot kernel.
    orth_apply_kernel<<<BATCH / (RPW * (BLOCK / 64)), BLOCK, 0, stream>>>(
        x, vn, d, bias, y);
}